// Round 18
// baseline (173.510 us; speedup 1.0000x reference)
//
#include <hip/hip_runtime.h>
#include <hip/hip_bf16.h>

// MoEBabyAIVLA — round 18: tail-concurrency pass. conv1/prep byte-identical
// to r17. conv2/conv3/fgemm M-tiles halved (2x blocks, same per-output
// accumulation order -> bit-identical): conv2 BM64 grid 1580, conv3 BM32
// grid 790, fgemm BM32 grid (16,4,9). All latency-bound 2-barrier loops get
// 2x block-level overlap.

typedef __bf16 bf16x8 __attribute__((ext_vector_type(8)));
typedef float f32x4 __attribute__((ext_vector_type(4)));

__device__ __forceinline__ unsigned short f2bf(float f) {
  union { float f; unsigned u; } v; v.f = f;
  unsigned r = v.u + 0x7FFFu + ((v.u >> 16) & 1u);
  return (unsigned short)(r >> 16);
}

__device__ __forceinline__ int wswz(int b) { return b ^ (((b >> 7) & 3) << 4); }

// ---------------- prep mega-kernel ----------------
// blocks [0,512)       : router (+lang fused) + logic mask + tail
// blocks [512,2080)    : conv weight reorder wb1/wb2/wb3
// blocks [2080,2179)   : fwT read-once transpose, 99 kblks of 64 k' each
__global__ __launch_bounds__(256) void prep_kernel(
    const int* __restrict__ text, const float* __restrict__ emb,
    const float* __restrict__ r_w1, const float* __restrict__ r_b1,
    const float* __restrict__ r_w2, const float* __restrict__ r_b2,
    const float* __restrict__ l_w1, const float* __restrict__ l_b1,
    const float* __restrict__ l_w2, const float* __restrict__ l_b2,
    const float* __restrict__ act_emb, const int* __restrict__ pa,
    const float* __restrict__ c1_w, const float* __restrict__ c2_w,
    const float* __restrict__ c3_w, const float* __restrict__ fw,
    float* __restrict__ rlog_out, int* __restrict__ eidx, float* __restrict__ lmask,
    unsigned short* __restrict__ tailb,
    unsigned short* __restrict__ wb1, unsigned short* __restrict__ wb2,
    unsigned short* __restrict__ wb3, unsigned short* __restrict__ fwT) {
  __shared__ __align__(16) unsigned short tl2[64][272];  // 34.8 KB
  const int blk = blockIdx.x;
  const int tid = threadIdx.x;

  if (blk < 512) {  // ---- router region ----
    int b = blk;
    int t = tid;
    __shared__ float lg[32];
    __shared__ float hr[64];
    __shared__ float hl[64];
    __shared__ float rl[12];
    __shared__ float lgc[256];

    if (t < 32) {  // EmbeddingBag mean
      const int* tb = text + b * 16;
      float s = 0.f;
#pragma unroll
      for (int tok = 0; tok < 16; ++tok) s += emb[tb[tok] * 32 + t];
      lg[t] = s * 0.0625f;
    }
    __syncthreads();

    if (t < 64) {
      float s1 = r_b1[t], s2 = l_b1[t];
      for (int k = 0; k < 32; ++k) {
        float lv = lg[k];
        s1 += lv * r_w1[k * 64 + t];
        s2 += lv * l_w1[k * 64 + t];
      }
      hr[t] = fmaxf(s1, 0.f);
      hl[t] = fmaxf(s2, 0.f);
    }
    if (t < 64) {  // tail row b: lang(32) | act(16) | zeros(16)
      float v = 0.f;
      if (t < 32) v = lg[t];
      else if (t < 48) v = act_emb[pa[b] * 16 + (t - 32)];
      tailb[b * 64 + t] = f2bf(v);
    }
    __syncthreads();

    if (t < 12) {
      float s = r_b2[t];
      for (int k = 0; k < 64; ++k) s += hr[k] * r_w2[k * 12 + t];
      rl[t] = s;
      rlog_out[b * 12 + t] = s;
    }
    {
      float s = l_b2[t];
      for (int k = 0; k < 64; ++k) s += hl[k] * l_w2[k * 256 + t];
      lgc[t] = s;
    }
    __syncthreads();

    if (t < 3) {  // top-1 per layer, stable
      int best = 0;
      float bv = rl[t * 4];
      for (int e = 1; e < 4; ++e) {
        float v = rl[t * 4 + e];
        if (v > bv) { bv = v; best = e; }
      }
      eidx[b * 3 + t] = best;
    }
    {  // top-32 mask via stable rank counting
      float v = lgc[t];
      int cnt = 0;
      for (int k = 0; k < 256; ++k) {
        float u = lgc[k];
        cnt += (u > v) || (u == v && k < t);
      }
      lmask[b * 256 + t] = (cnt < 32) ? 1.f : 0.f;
    }
  } else if (blk < 2080) {  // ---- conv weights, k' = g*CIN+ci ----
    int idx = (blk - 512) * 256 + tid;  // 401408
    if (idx < 24576) {
      int k = idx % 192, ec = idx / 192;
      float v = 0.f;
      if (k < 144) {
        int g = k >> 4, ci = k & 15;
        if (ci < 12) v = c1_w[ec * 108 + ci * 9 + g];
      }
      wb1[idx] = f2bf(v);
    } else if (idx < 106496) {
      int i2 = idx - 24576;
      int k = i2 % 320, ec = i2 / 320;
      float v = 0.f;
      if (k < 288) {
        int g = k >> 5, ci = k & 31;
        v = c2_w[ec * 288 + ci * 9 + g];
      }
      wb2[i2] = f2bf(v);
    } else {
      int i3 = idx - 106496;
      int k = i3 % 576, ec = i3 / 576;
      int g = k >> 6, ci = k & 63;
      wb3[i3] = f2bf(c3_w[ec * 576 + ci * 9 + g]);
    }
  } else {  // ---- fwT read-once: block kb handles k' in [kb*64, kb*64+64) ----
    int kb = blk - 2080;          // 0..98
    int k0 = kb * 64;
#pragma unroll
    for (int rg = 0; rg < 4; ++rg) {
      int rl = rg * 16 + (tid >> 4);
      int srow;
      bool valid;
      if (kb < 98) {              // k' = p*128 + co; co = (kb&1)*64+rl, p = kb>>1
        srow = ((kb & 1) * 64 + rl) * 49 + (kb >> 1);
        valid = true;
      } else {                    // tail rows 6272..6319, zeros beyond
        srow = 6272 + rl;
        valid = (rl < 48);
      }
#pragma unroll
      for (int c = 0; c < 4; ++c) {
        int col = ((tid & 15) + c * 16) * 4;
        float4 v = valid ? *(const float4*)&fw[(size_t)srow * 256 + col]
                         : (float4){0.f, 0.f, 0.f, 0.f};
        tl2[rl][col + 0] = f2bf(v.x);
        tl2[rl][col + 1] = f2bf(v.y);
        tl2[rl][col + 2] = f2bf(v.z);
        tl2[rl][col + 3] = f2bf(v.w);
      }
    }
    __syncthreads();
#pragma unroll
    for (int np = 0; np < 4; ++np) {
      int n = np * 64 + (tid >> 2);
      int kc = (tid & 3) * 16;
      unsigned short vv[16];
#pragma unroll
      for (int i = 0; i < 16; ++i) vv[i] = tl2[kc + i][n];
      unsigned short* dst = fwT + (size_t)n * 6336 + k0 + kc;
      *(uint4*)dst = *(const uint4*)&vv[0];
      *(uint4*)(dst + 8) = *(const uint4*)&vv[8];
    }
  }
}

// ---------------- conv1 fused + bucket region (r17, unchanged) ----------------
__global__ __launch_bounds__(256, 4) void conv1_fused(
    const float* __restrict__ img, const unsigned short* __restrict__ wb,
    const float* __restrict__ bias, const int* __restrict__ eidx,
    unsigned short* __restrict__ out, int* __restrict__ cnt,
    int* __restrict__ perm) {
  __shared__ __align__(16) char win[25536];    // 14*57*16 u16, swizzled
  __shared__ __align__(16) char ldsB[3 * 4096];
  const int tid = threadIdx.x;

  if (blockIdx.x >= 3584) {  // ---- bucket region ----
    int* el = (int*)win;     // 512 ints
    int* cc = el + 512;      // 4 ints
    int l = blockIdx.x - 3584;
    el[tid] = eidx[tid * 3 + l];
    el[tid + 256] = eidx[(tid + 256) * 3 + l];
    __syncthreads();
    if (tid < 4) {
      int c = 0;
      for (int b = 0; b < 512; ++b) c += (el[b] == tid);
      cc[tid] = c;
      cnt[l * 4 + tid] = c;
    }
    __syncthreads();
#pragma unroll
    for (int rep = 0; rep < 2; ++rep) {
      int b = tid + rep * 256;
      int e = el[b];
      int rank = 0;
      for (int bp = 0; bp < b; ++bp) rank += (el[bp] == e);
      int off = 0;
      for (int ee = 0; ee < e; ++ee) off += cc[ee];
      perm[l * 512 + off + rank] = b;
    }
    return;
  }

  // XCD-aware decode: tiles of one sample -> same XCD
  const int xcd = blockIdx.x & 7;
  const int u = blockIdx.x >> 3;
  const int t = u % 7;
  const int s = (u / 7) * 8 + xcd;
  const int e = eidx[s * 3];
  const int lane = tid & 63;
  const int wid = tid >> 6;
  const int wm0 = wid * 32;  // WGM=4, WGN=1, MF=2, NF=2

  const int p0 = t * 128;
  const int ohmin = p0 / 28;
  const int ih0 = ohmin * 2 - 1;

  // ---- phase 0: issue ALL global loads (fill + B-stage) before any LDS work
  const float* ibase = img + (size_t)s * 37632;
  float vv[9][4];
  int bp9[9];
  bool ok9[9];
#pragma unroll
  for (int it = 0; it < 9; ++it) {
    int c = tid + it * 256;
    int q = c / 728;
    int rem = c - q * 728;
    int ihl = rem / 56;
    int iw = rem - ihl * 56;
    int ih = ih0 + ihl;
    bool ok = (c < 2184) && ((unsigned)ih < 56u);
    ok9[it] = ok;
    bp9[it] = (ihl * 57 + iw + 1) * 32 + q * 8;
    if (ok) {
      const float* src = ibase + q * 12544 + ih * 56 + iw;
      vv[it][0] = src[0];
      vv[it][1] = src[3136];
      vv[it][2] = src[6272];
      vv[it][3] = src[9408];
    }
  }
  uint4 bstg[3];
  int bdst[3];
  {
    const unsigned short* wbe = wb + e * (32 * 192);
#pragma unroll
    for (int c = 0; c < 3; ++c) {
      int cc = tid + 256 * c;          // 768 chunks: 32 rows x 24
      int n = cc / 24, cb = cc - n * 24;
      int kt = cb >> 3, cbl = cb & 7;
      bstg[c] = *(const uint4*)(wbe + n * 192 + cb * 8);
      bdst[c] = kt * 4096 + n * 128 + ((cbl * 16) ^ ((n & 7) << 4));
    }
  }
  __builtin_amdgcn_sched_barrier(0);  // pin: loads above, LDS work below

  // zero whole window
  {
    uint4 z; z.x = z.y = z.z = z.w = 0u;
    for (int i = tid; i < 1596; i += 256) ((uint4*)win)[i] = z;
  }
  // write staged B
#pragma unroll
  for (int c = 0; c < 3; ++c) *(uint4*)(ldsB + bdst[c]) = bstg[c];
  __syncthreads();

  // fill writes
#pragma unroll
  for (int it = 0; it < 9; ++it) {
    if (ok9[it]) {
      unsigned short w4[4] = {f2bf(vv[it][0]), f2bf(vv[it][1]),
                              f2bf(vv[it][2]), f2bf(vv[it][3])};
      *(unsigned long long*)(win + wswz(bp9[it])) = *(const unsigned long long*)w4;
    }
  }

  // per-row constants
  int ohl[2], owr[2];
#pragma unroll
  for (int mf = 0; mf < 2; ++mf) {
    int m = wm0 + mf * 16 + (lane & 15);
    int p = p0 + m;
    if (p > 783) p = 783;
    int oh = p / 28;
    owr[mf] = p - oh * 28;
    ohl[mf] = (oh - ohmin) * 2;
  }
  const int lg = lane >> 4;
  const int ci0 = (lg & 1) * 8;
  const int lgh = lg >> 1;
  int brdo[2], brx[2];
#pragma unroll
  for (int nf = 0; nf < 2; ++nf) {
    int n = nf * 16 + (lane & 15);
    brdo[nf] = n * 128;
    brx[nf] = (n & 7) << 4;
  }

  f32x4 acc[2][2];
#pragma unroll
  for (int mf = 0; mf < 2; ++mf)
#pragma unroll
    for (int nf = 0; nf < 2; ++nf) acc[mf][nf] = (f32x4){0.f, 0.f, 0.f, 0.f};

  __syncthreads();

#pragma unroll
  for (int kt = 0; kt < 3; ++kt) {
#pragma unroll
    for (int ks = 0; ks < 2; ++ks) {
      const int g = kt * 4 + ks * 2 + lgh;
      const int kh = g / 3;
      const int kw = g - kh * 3;
      const bool gv = (g < 9);
      bf16x8 af[2];
#pragma unroll
      for (int mf = 0; mf < 2; ++mf) {
        int iwp = owr[mf] * 2 + kw;
        int ihl = ohl[mf] + kh;
        int bp = gv ? ((ihl * 57 + iwp) * 32 + ci0 * 2)
                    : (13 * 57 * 32 + ci0 * 2);
        af[mf] = __builtin_bit_cast(bf16x8, *(const uint4*)(win + wswz(bp)));
      }
      bf16x8 bfv[2];
      const int cb = ks * 64 + ((lane >> 4) << 4);
#pragma unroll
      for (int nf = 0; nf < 2; ++nf)
        bfv[nf] = __builtin_bit_cast(bf16x8,
            *(const uint4*)(ldsB + kt * 4096 + brdo[nf] + (cb ^ brx[nf])));
#pragma unroll
      for (int mf = 0; mf < 2; ++mf)
#pragma unroll
        for (int nf = 0; nf < 2; ++nf)
          acc[mf][nf] = __builtin_amdgcn_mfma_f32_16x16x32_bf16(af[mf], bfv[nf], acc[mf][nf], 0, 0, 0);
    }
  }

  const int col = lane & 15;
  const int rg = (lane >> 4) * 4;
  const float b0 = bias[e * 32 + col];
  const float b1 = bias[e * 32 + 16 + col];
#pragma unroll
  for (int mf = 0; mf < 2; ++mf)
#pragma unroll
    for (int r = 0; r < 4; ++r) {
      int m = wm0 + mf * 16 + rg + r;
      int p = p0 + m;
      if (p < 784) {
        size_t ob = ((size_t)s * 784 + p) * 32;
        out[ob + col]      = f2bf(fmaxf(acc[mf][0][r] + b0, 0.f));
        out[ob + 16 + col] = f2bf(fmaxf(acc[mf][1][r] + b1, 0.f));
      }
    }
}

// ---------------- conv as implicit-GEMM MFMA (bf16 NHWC) — conv2/conv3 ----------------
template<int CIN, int H, int OH, int KREAL, int KP, int COUT,
         int WGM, int WGN, int MF, int NF>
__global__ __launch_bounds__(256) void conv_mfma(
    const unsigned short* __restrict__ in, const unsigned short* __restrict__ wb,
    const float* __restrict__ bias, const int* __restrict__ cnt,
    const int* __restrict__ perm, unsigned short* __restrict__ out) {
  constexpr int PerS = OH * OH;
  constexpr int BM = WGM * MF * 16;
  constexpr int BN = WGN * NF * 16;
  constexpr int AJ = BM / 32;
  constexpr int KT = KP / 64;
  constexpr int W = H;
  constexpr int BCH = BN / 32;

  int bm = blockIdx.x;
  int e = 0, row0 = 0, rows = 0;
  bool found = false;
  {
    int acc = 0, ebase = 0;
#pragma unroll
    for (int ee = 0; ee < 4; ++ee) {
      int er = cnt[ee] * PerS;
      int te = (er + BM - 1) / BM;
      if (!found && bm < acc + te) {
        e = ee;
        row0 = ebase + (bm - acc) * BM;
        rows = er - (bm - acc) * BM;
        if (rows > BM) rows = BM;
        found = true;
      }
      acc += te;
      ebase += er;
    }
  }
  if (!found) return;

  __shared__ __align__(16) char lds[BM * 128 + BN * 128];
  char* ldsB = lds + BM * 128;
  const int tid = threadIdx.x;
  const int lane = tid & 63;
  const int wid = tid >> 6;
  const int wm0 = (wid / WGN) * (MF * 16);
  const int wn0 = (wid % WGN) * (NF * 16);
  const int c16 = tid & 7;

  int ihc[AJ], iwc[AJ], abase[AJ], adso[AJ];
#pragma unroll
  for (int j = 0; j < AJ; ++j) {
    int r = (tid >> 3) + 32 * j;
    int gr = row0 + r;
    const int MAXR = 512 * PerS - 1;
    if (gr > MAXR) gr = MAXR;
    int sord = gr / PerS;
    int p = gr - sord * PerS;
    int s = perm[sord];
    int oh = p / OH, ow = p - oh * OH;
    ihc[j] = oh * 2 - 1;
    iwc[j] = ow * 2 - 1;
    abase[j] = s * (H * W);
    adso[j] = r * 128 + ((c16 * 16) ^ ((r & 7) << 4));
  }
  const unsigned short* wbe = wb + (size_t)e * COUT * KP;
  int bgo[BCH], bdso[BCH];
#pragma unroll
  for (int c = 0; c < BCH; ++c) {
    int cc = tid + 256 * c;
    int n = cc >> 3, cb = cc & 7;
    bgo[c] = n * KP + cb * 8;
    bdso[c] = n * 128 + ((cb * 16) ^ ((n & 7) << 4));
  }
  int ardo[MF], arx[MF], brdo[NF], brx[NF];
#pragma unroll
  for (int mf = 0; mf < MF; ++mf) {
    int r = wm0 + mf * 16 + (lane & 15);
    ardo[mf] = r * 128;
    arx[mf] = (r & 7) << 4;
  }
#pragma unroll
  for (int nf = 0; nf < NF; ++nf) {
    int n = wn0 + nf * 16 + (lane & 15);
    brdo[nf] = n * 128;
    brx[nf] = (n & 7) << 4;
  }

  auto loadA = [&](int kt, int j) -> uint4 {
    uint4 z; z.x = z.y = z.z = z.w = 0u;
    int kbase = kt * 64 + c16 * 8;
    if (kbase >= KREAL) return z;
    int g = kbase / CIN;
    int ci0 = kbase - g * CIN;
    int kh = g / 3, kw = g - (g / 3) * 3;
    int ih = ihc[j] + kh, iw = iwc[j] + kw;
    if ((unsigned)ih >= (unsigned)H || (unsigned)iw >= (unsigned)W) return z;
    const unsigned short* p = in + ((size_t)(abase[j] + ih * W + iw) * CIN + ci0);
    return *(const uint4*)p;
  };

  uint4 rA[AJ], rB[BCH];
#pragma unroll
  for (int j = 0; j < AJ; ++j) rA[j] = loadA(0, j);
#pragma unroll
  for (int c = 0; c < BCH; ++c) rB[c] = *(const uint4*)(wbe + bgo[c]);

  f32x4 acc[MF][NF];
#pragma unroll
  for (int mf = 0; mf < MF; ++mf)
#pragma unroll
    for (int nf = 0; nf < NF; ++nf) acc[mf][nf] = (f32x4){0.f, 0.f, 0.f, 0.f};

  for (int kt = 0; kt < KT; ++kt) {
    __syncthreads();
#pragma unroll
    for (int j = 0; j < AJ; ++j) *(uint4*)(lds + adso[j]) = rA[j];
#pragma unroll
    for (int c = 0; c < BCH; ++c) *(uint4*)(ldsB + bdso[c]) = rB[c];
    __syncthreads();
    if (kt + 1 < KT) {
#pragma unroll
      for (int j = 0; j < AJ; ++j) rA[j] = loadA(kt + 1, j);
#pragma unroll
      for (int c = 0; c < BCH; ++c) rB[c] = *(const uint4*)(wbe + bgo[c] + (kt + 1) * 64);
    }
#pragma unroll
    for (int ks = 0; ks < 2; ++ks) {
      int cb = ks * 64 + ((lane >> 4) << 4);
      bf16x8 af[MF], bfv[NF];
#pragma unroll
      for (int mf = 0; mf < MF; ++mf)
        af[mf] = __builtin_bit_cast(bf16x8, *(const uint4*)(lds + ardo[mf] + (cb ^ arx[mf])));
#pragma unroll
      for (int nf = 0; nf < NF; ++nf)
        bfv[nf] = __builtin_bit_cast(bf16x8, *(const uint4*)(ldsB + brdo[nf] + (cb ^ brx[nf])));
#pragma unroll
      for (int mf = 0; mf < MF; ++mf)
#pragma unroll
        for (int nf = 0; nf < NF; ++nf)
          acc[mf][nf] = __builtin_amdgcn_mfma_f32_16x16x32_bf16(af[mf], bfv[nf], acc[mf][nf], 0, 0, 0);
    }
  }

  const int col = lane & 15;
  const int rg = (lane >> 4) * 4;
#pragma unroll
  for (int mf = 0; mf < MF; ++mf) {
#pragma unroll
    for (int r = 0; r < 4; ++r) {
      int m = wm0 + mf * 16 + rg + r;
      if (m < rows) {
        int gr = row0 + m;
        int sord = gr / PerS;
        int p = gr - sord * PerS;
        int s = perm[sord];
        size_t ob = ((size_t)s * PerS + p) * COUT;
#pragma unroll
        for (int nf = 0; nf < NF; ++nf) {
          int co = wn0 + nf * 16 + col;
          float v = acc[mf][nf][r] + bias[e * COUT + co];
          out[ob + co] = f2bf(fmaxf(v, 0.f));
        }
      }
    }
  }
}

// ---------------- fused GEMM [512,6336]x[6336,256], 32x64 tiles, split-K=9 ----------------
__global__ __launch_bounds__(256) void fgemm_kernel(
    const unsigned short* __restrict__ x3, const unsigned short* __restrict__ tail,
    const unsigned short* __restrict__ fwT, float* __restrict__ partial) {
  constexpr int NF = 2;
  const int row0 = blockIdx.x * 32;
  const int nc0 = blockIdx.y * 64;
  const int kz = blockIdx.z * 704;
  __shared__ __align__(16) char lds[32 * 128 + 64 * 128];
  char* ldsB = lds + 32 * 128;
  const int tid = threadIdx.x;
  const int lane = tid & 63;
  const int wid = tid >> 6;
  const int wm0 = (wid >> 1) * 16;   // 2 M-groups x 16 rows
  const int wn0 = (wid & 1) * 32;
  const int c16 = tid & 7;
  int arow, adso;
  {
    int r = tid >> 3;                 // 32 rows x 8 chunks
    arow = row0 + r;
    adso = r * 128 + ((c16 * 16) ^ ((r & 7) << 4));
  }
  int bgo[2], bdso[2];
#pragma unroll
  for (int c = 0; c < 2; ++c) {
    int cc = tid + 256 * c;
    int n = cc >> 3, cb = cc & 7;
    bgo[c] = (nc0 + n) * 6336 + kz + cb * 8;
    bdso[c] = n * 128 + ((cb * 16) ^ ((n & 7) << 4));
  }
  int ardo, arx, brdo[NF], brx[NF];
  {
    int r = wm0 + (lane & 15);
    ardo = r * 128; arx = (r & 7) << 4;
  }
#pragma unroll
  for (int nf = 0; nf < NF; ++nf) {
    int n = wn0 + nf * 16 + (lane & 15);
    brdo[nf] = n * 128; brx[nf] = (n & 7) << 4;
  }
  auto loadA = [&](int kt) -> uint4 {
    int k = kz + kt * 64 + c16 * 8;
    const unsigned short* p;
    if (k < 6272) p = x3 + (size_t)arow * 6272 + k;
    else p = tail + arow * 64 + (k - 6272);
    return *(const uint4*)p;
  };
  uint4 rA, rB[2];
  rA = loadA(0);
#pragma unroll
  for (int c = 0; c < 2; ++c) rB[c] = *(const uint4*)(fwT + bgo[c]);
  f32x4 acc[NF];
#pragma unroll
  for (int nf = 0; nf < NF; ++nf) acc[nf] = (f32x4){0.f, 0.f, 0.f, 0.f};

  for (int kt = 0; kt < 11; ++kt) {
    __syncthreads();
    *(uint4*)(lds + adso) = rA;
#pragma unroll
    for (int c = 0; c < 2; ++c) *(uint4*)(ldsB + bdso[c]) = rB[c];
    __syncthreads();
    if (kt + 1 < 11) {
      rA = loadA(kt + 1);
#pragma unroll
      for (int c = 0; c < 2; ++c) rB[c] = *(const uint4*)(fwT + bgo[c] + (kt + 1) * 64);
    }
#pragma unroll
    for (int ks = 0; ks < 2; ++ks) {
      int cb = ks * 64 + ((lane >> 4) << 4);
      bf16x8 af = __builtin_bit_cast(bf16x8, *(const uint4*)(lds + ardo + (cb ^ arx)));
      bf16x8 bfv[NF];
#pragma unroll
      for (int nf = 0; nf < NF; ++nf)
        bfv[nf] = __builtin_bit_cast(bf16x8, *(const uint4*)(ldsB + brdo[nf] + (cb ^ brx[nf])));
#pragma unroll
      for (int nf = 0; nf < NF; ++nf)
        acc[nf] = __builtin_amdgcn_mfma_f32_16x16x32_bf16(af, bfv[nf], acc[nf], 0, 0, 0);
    }
  }
  const int col = lane & 15;
  const int rg = (lane >> 4) * 4;
  float* pz = partial + (size_t)blockIdx.z * 131072;
#pragma unroll
  for (int r = 0; r < 4; ++r) {
    int m = wm0 + rg + r;
    int grow = row0 + m;
#pragma unroll
    for (int nf = 0; nf < NF; ++nf) {
      int n = nc0 + wn0 + nf * 16 + col;
      pz[grow * 256 + n] = acc[nf][r];
    }
  }
}

// ---------------- reduce + head merged ----------------
__global__ __launch_bounds__(256) void reduce_head(const float* __restrict__ part,
                                                   const float* __restrict__ f_b,
                                                   const float* __restrict__ lmask,
                                                   const float* __restrict__ h_w,
                                                   const float* __restrict__ h_b,
                                                   float* __restrict__ logits) {
  int b = blockIdx.x, t = threadIdx.x;
  float s = f_b[t];
#pragma unroll
  for (int z = 0; z < 9; ++z) s += part[z * 131072 + b * 256 + t];
  __shared__ float o[256];
  o[t] = (lmask[b * 256 + t] != 0.f) ? fmaxf(s, 0.f) : 0.f;
  __syncthreads();
  if (t < 5) {
    float v = h_b[t];
    for (int n = 0; n < 256; ++n) v += o[n] * h_w[n * 5 + t];
    logits[b * 5 + t] = v;
  }
}

extern "C" void kernel_launch(void* const* d_in, const int* in_sizes, int n_in,
                              void* d_out, int out_size, void* d_ws, size_t ws_size,
                              hipStream_t stream) {
  (void)in_sizes; (void)n_in; (void)out_size; (void)ws_size;
  const float* img       = (const float*)d_in[0];
  const int*   text      = (const int*)d_in[1];
  const int*   pa        = (const int*)d_in[2];
  const float* emb_table = (const float*)d_in[3];
  const float* r_w1 = (const float*)d_in[4];
  const float* r_b1 = (const float*)d_in[5];
  const float* r_w2 = (const float*)d_in[6];
  const float* r_b2 = (const float*)d_in[7];
  const float* l_w1 = (const float*)d_in[8];
  const float* l_b1 = (const float*)d_in[9];
  const float* l_w2 = (const float*)d_in[10];
  const float* l_b2 = (const float*)d_in[11];
  const float* c1_w = (const float*)d_in[12];
  const float* c1_b = (const float*)d_in[13];
  const float* c2_w = (const float*)d_in[14];
  const float* c2_b = (const float*)d_in[15];
  const float* c3_w = (const float*)d_in[16];
  const float* c3_b = (const float*)d_in[17];
  const float* act_emb = (const float*)d_in[18];
  const float* f_w = (const float*)d_in[19];
  const float* f_b = (const float*)d_in[20];
  const float* h_w = (const float*)d_in[21];
  const float* h_b = (const float*)d_in[22];

  float* outf   = (float*)d_out;
  float* logits = outf;             // [512,5]
  float* rlog   = outf + 2560;      // [512,3,4]

  char* cur = (char*)d_ws;
  auto alloc = [&](size_t bytes) { char* r = cur; cur += (bytes + 255) & ~(size_t)255; return r; };
  float* lmask   = (float*)alloc(131072 * 4);
  int* eidx      = (int*)alloc(1536 * 4);
  int* cnt       = (int*)alloc(12 * 4);
  int* perm      = (int*)alloc(1536 * 4);
  unsigned short* wb1  = (unsigned short*)alloc((size_t)24576 * 2);
  unsigned short* wb2  = (unsigned short*)alloc((size_t)81920 * 2);
  unsigned short* wb3  = (unsigned short*)alloc((size_t)294912 * 2);
  unsigned short* fwT  = (unsigned short*)alloc((size_t)1622016 * 2);
  unsigned short* tailb= (unsigned short*)alloc((size_t)32768 * 2);
  unsigned short* x1b  = (unsigned short*)alloc((size_t)12845056 * 2);
  unsigned short* x2b  = (unsigned short*)alloc((size_t)6422528 * 2);
  unsigned short* x3b  = (unsigned short*)alloc((size_t)3211264 * 2);
  float* partial       = (float*)alloc((size_t)9 * 131072 * 4);

  prep_kernel<<<2179, 256, 0, stream>>>(text, emb_table,
                                        r_w1, r_b1, r_w2, r_b2,
                                        l_w1, l_b1, l_w2, l_b2,
                                        act_emb, pa,
                                        c1_w, c2_w, c3_w, f_w,
                                        rlog, eidx, lmask, tailb,
                                        wb1, wb2, wb3, fwT);

  conv1_fused<<<3587, 256, 0, stream>>>(img, wb1, c1_b, eidx, x1b, cnt, perm);
  conv_mfma<32, 28, 14, 288, 320, 64, 2, 2, 2, 2>
      <<<1580, 256, 0, stream>>>(x1b, wb2, c2_b, cnt + 4, perm + 512, x2b);
  conv_mfma<64, 14, 7, 576, 576, 128, 1, 4, 2, 2>
      <<<790, 256, 0, stream>>>(x2b, wb3, c3_b, cnt + 8, perm + 1024, x3b);

  fgemm_kernel<<<dim3(16, 4, 9), 256, 0, stream>>>(x3b, tailb, fwT, partial);
  reduce_head<<<512, 256, 0, stream>>>(partial, f_b, lmask, h_w, h_b, logits);
}

// Round 19
// 137.798 us; speedup vs baseline: 1.2592x; 1.2592x over previous
//
#include <hip/hip_runtime.h>
#include <hip/hip_bf16.h>

// MoEBabyAIVLA — round 19 (FINAL): exact restore of round-17 configuration,
// the best measured (138.06 us). Revert of r18's tail-tile regression.
// Pipeline: prep (router + weight reorders + fwT transpose) ->
// conv1_fused (bf16 MFMA, fused NCHW->NHWC, XCD-swizzled, split-phase loads,
// +bucket region) -> conv2/conv3 (expert-bucketed implicit-GEMM MFMA) ->
// fgemm (split-K=9) -> reduce_head.

typedef __bf16 bf16x8 __attribute__((ext_vector_type(8)));
typedef float f32x4 __attribute__((ext_vector_type(4)));

__device__ __forceinline__ unsigned short f2bf(float f) {
  union { float f; unsigned u; } v; v.f = f;
  unsigned r = v.u + 0x7FFFu + ((v.u >> 16) & 1u);
  return (unsigned short)(r >> 16);
}

__device__ __forceinline__ int wswz(int b) { return b ^ (((b >> 7) & 3) << 4); }

// ---------------- prep mega-kernel ----------------
// blocks [0,512)       : router (+lang fused) + logic mask + tail
// blocks [512,2080)    : conv weight reorder wb1/wb2/wb3
// blocks [2080,2179)   : fwT read-once transpose, 99 kblks of 64 k' each
__global__ __launch_bounds__(256) void prep_kernel(
    const int* __restrict__ text, const float* __restrict__ emb,
    const float* __restrict__ r_w1, const float* __restrict__ r_b1,
    const float* __restrict__ r_w2, const float* __restrict__ r_b2,
    const float* __restrict__ l_w1, const float* __restrict__ l_b1,
    const float* __restrict__ l_w2, const float* __restrict__ l_b2,
    const float* __restrict__ act_emb, const int* __restrict__ pa,
    const float* __restrict__ c1_w, const float* __restrict__ c2_w,
    const float* __restrict__ c3_w, const float* __restrict__ fw,
    float* __restrict__ rlog_out, int* __restrict__ eidx, float* __restrict__ lmask,
    unsigned short* __restrict__ tailb,
    unsigned short* __restrict__ wb1, unsigned short* __restrict__ wb2,
    unsigned short* __restrict__ wb3, unsigned short* __restrict__ fwT) {
  __shared__ __align__(16) unsigned short tl2[64][272];  // 34.8 KB
  const int blk = blockIdx.x;
  const int tid = threadIdx.x;

  if (blk < 512) {  // ---- router region ----
    int b = blk;
    int t = tid;
    __shared__ float lg[32];
    __shared__ float hr[64];
    __shared__ float hl[64];
    __shared__ float rl[12];
    __shared__ float lgc[256];

    if (t < 32) {  // EmbeddingBag mean
      const int* tb = text + b * 16;
      float s = 0.f;
#pragma unroll
      for (int tok = 0; tok < 16; ++tok) s += emb[tb[tok] * 32 + t];
      lg[t] = s * 0.0625f;
    }
    __syncthreads();

    if (t < 64) {
      float s1 = r_b1[t], s2 = l_b1[t];
      for (int k = 0; k < 32; ++k) {
        float lv = lg[k];
        s1 += lv * r_w1[k * 64 + t];
        s2 += lv * l_w1[k * 64 + t];
      }
      hr[t] = fmaxf(s1, 0.f);
      hl[t] = fmaxf(s2, 0.f);
    }
    if (t < 64) {  // tail row b: lang(32) | act(16) | zeros(16)
      float v = 0.f;
      if (t < 32) v = lg[t];
      else if (t < 48) v = act_emb[pa[b] * 16 + (t - 32)];
      tailb[b * 64 + t] = f2bf(v);
    }
    __syncthreads();

    if (t < 12) {
      float s = r_b2[t];
      for (int k = 0; k < 64; ++k) s += hr[k] * r_w2[k * 12 + t];
      rl[t] = s;
      rlog_out[b * 12 + t] = s;
    }
    {
      float s = l_b2[t];
      for (int k = 0; k < 64; ++k) s += hl[k] * l_w2[k * 256 + t];
      lgc[t] = s;
    }
    __syncthreads();

    if (t < 3) {  // top-1 per layer, stable
      int best = 0;
      float bv = rl[t * 4];
      for (int e = 1; e < 4; ++e) {
        float v = rl[t * 4 + e];
        if (v > bv) { bv = v; best = e; }
      }
      eidx[b * 3 + t] = best;
    }
    {  // top-32 mask via stable rank counting
      float v = lgc[t];
      int cnt = 0;
      for (int k = 0; k < 256; ++k) {
        float u = lgc[k];
        cnt += (u > v) || (u == v && k < t);
      }
      lmask[b * 256 + t] = (cnt < 32) ? 1.f : 0.f;
    }
  } else if (blk < 2080) {  // ---- conv weights, k' = g*CIN+ci ----
    int idx = (blk - 512) * 256 + tid;  // 401408
    if (idx < 24576) {
      int k = idx % 192, ec = idx / 192;
      float v = 0.f;
      if (k < 144) {
        int g = k >> 4, ci = k & 15;
        if (ci < 12) v = c1_w[ec * 108 + ci * 9 + g];
      }
      wb1[idx] = f2bf(v);
    } else if (idx < 106496) {
      int i2 = idx - 24576;
      int k = i2 % 320, ec = i2 / 320;
      float v = 0.f;
      if (k < 288) {
        int g = k >> 5, ci = k & 31;
        v = c2_w[ec * 288 + ci * 9 + g];
      }
      wb2[i2] = f2bf(v);
    } else {
      int i3 = idx - 106496;
      int k = i3 % 576, ec = i3 / 576;
      int g = k >> 6, ci = k & 63;
      wb3[i3] = f2bf(c3_w[ec * 576 + ci * 9 + g]);
    }
  } else {  // ---- fwT read-once: block kb handles k' in [kb*64, kb*64+64) ----
    int kb = blk - 2080;          // 0..98
    int k0 = kb * 64;
#pragma unroll
    for (int rg = 0; rg < 4; ++rg) {
      int rl = rg * 16 + (tid >> 4);
      int srow;
      bool valid;
      if (kb < 98) {              // k' = p*128 + co; co = (kb&1)*64+rl, p = kb>>1
        srow = ((kb & 1) * 64 + rl) * 49 + (kb >> 1);
        valid = true;
      } else {                    // tail rows 6272..6319, zeros beyond
        srow = 6272 + rl;
        valid = (rl < 48);
      }
#pragma unroll
      for (int c = 0; c < 4; ++c) {
        int col = ((tid & 15) + c * 16) * 4;
        float4 v = valid ? *(const float4*)&fw[(size_t)srow * 256 + col]
                         : (float4){0.f, 0.f, 0.f, 0.f};
        tl2[rl][col + 0] = f2bf(v.x);
        tl2[rl][col + 1] = f2bf(v.y);
        tl2[rl][col + 2] = f2bf(v.z);
        tl2[rl][col + 3] = f2bf(v.w);
      }
    }
    __syncthreads();
#pragma unroll
    for (int np = 0; np < 4; ++np) {
      int n = np * 64 + (tid >> 2);
      int kc = (tid & 3) * 16;
      unsigned short vv[16];
#pragma unroll
      for (int i = 0; i < 16; ++i) vv[i] = tl2[kc + i][n];
      unsigned short* dst = fwT + (size_t)n * 6336 + k0 + kc;
      *(uint4*)dst = *(const uint4*)&vv[0];
      *(uint4*)(dst + 8) = *(const uint4*)&vv[8];
    }
  }
}

// ---------------- conv1 fused + bucket region ----------------
// blocks [0,3584): conv1, XCD-swizzled: xcd=bx&7, u=bx>>3, t=u%7, s=(u/7)*8+xcd
// blocks [3584,3587): bucket layer l (stable counting sort; feeds conv2/3)
__global__ __launch_bounds__(256, 4) void conv1_fused(
    const float* __restrict__ img, const unsigned short* __restrict__ wb,
    const float* __restrict__ bias, const int* __restrict__ eidx,
    unsigned short* __restrict__ out, int* __restrict__ cnt,
    int* __restrict__ perm) {
  __shared__ __align__(16) char win[25536];    // 14*57*16 u16, swizzled
  __shared__ __align__(16) char ldsB[3 * 4096];
  const int tid = threadIdx.x;

  if (blockIdx.x >= 3584) {  // ---- bucket region ----
    int* el = (int*)win;     // 512 ints
    int* cc = el + 512;      // 4 ints
    int l = blockIdx.x - 3584;
    el[tid] = eidx[tid * 3 + l];
    el[tid + 256] = eidx[(tid + 256) * 3 + l];
    __syncthreads();
    if (tid < 4) {
      int c = 0;
      for (int b = 0; b < 512; ++b) c += (el[b] == tid);
      cc[tid] = c;
      cnt[l * 4 + tid] = c;
    }
    __syncthreads();
#pragma unroll
    for (int rep = 0; rep < 2; ++rep) {
      int b = tid + rep * 256;
      int e = el[b];
      int rank = 0;
      for (int bp = 0; bp < b; ++bp) rank += (el[bp] == e);
      int off = 0;
      for (int ee = 0; ee < e; ++ee) off += cc[ee];
      perm[l * 512 + off + rank] = b;
    }
    return;
  }

  // XCD-aware decode: tiles of one sample -> same XCD
  const int xcd = blockIdx.x & 7;
  const int u = blockIdx.x >> 3;
  const int t = u % 7;
  const int s = (u / 7) * 8 + xcd;
  const int e = eidx[s * 3];
  const int lane = tid & 63;
  const int wid = tid >> 6;
  const int wm0 = wid * 32;  // WGM=4, WGN=1, MF=2, NF=2

  const int p0 = t * 128;
  const int ohmin = p0 / 28;
  const int ih0 = ohmin * 2 - 1;

  // ---- phase 0: issue ALL global loads (fill + B-stage) before any LDS work
  const float* ibase = img + (size_t)s * 37632;
  float vv[9][4];
  int bp9[9];
  bool ok9[9];
#pragma unroll
  for (int it = 0; it < 9; ++it) {
    int c = tid + it * 256;
    int q = c / 728;
    int rem = c - q * 728;
    int ihl = rem / 56;
    int iw = rem - ihl * 56;
    int ih = ih0 + ihl;
    bool ok = (c < 2184) && ((unsigned)ih < 56u);
    ok9[it] = ok;
    bp9[it] = (ihl * 57 + iw + 1) * 32 + q * 8;
    if (ok) {
      const float* src = ibase + q * 12544 + ih * 56 + iw;
      vv[it][0] = src[0];
      vv[it][1] = src[3136];
      vv[it][2] = src[6272];
      vv[it][3] = src[9408];
    }
  }
  uint4 bstg[3];
  int bdst[3];
  {
    const unsigned short* wbe = wb + e * (32 * 192);
#pragma unroll
    for (int c = 0; c < 3; ++c) {
      int cc = tid + 256 * c;          // 768 chunks: 32 rows x 24
      int n = cc / 24, cb = cc - n * 24;
      int kt = cb >> 3, cbl = cb & 7;
      bstg[c] = *(const uint4*)(wbe + n * 192 + cb * 8);
      bdst[c] = kt * 4096 + n * 128 + ((cbl * 16) ^ ((n & 7) << 4));
    }
  }
  __builtin_amdgcn_sched_barrier(0);  // pin: loads above, LDS work below

  // zero whole window (pads, halo col, zero row 13, ci 12-15 tails)
  {
    uint4 z; z.x = z.y = z.z = z.w = 0u;
    for (int i = tid; i < 1596; i += 256) ((uint4*)win)[i] = z;
  }
  // write staged B
#pragma unroll
  for (int c = 0; c < 3; ++c) *(uint4*)(ldsB + bdst[c]) = bstg[c];
  __syncthreads();

  // fill writes (loads already in flight / landed)
#pragma unroll
  for (int it = 0; it < 9; ++it) {
    if (ok9[it]) {
      unsigned short w4[4] = {f2bf(vv[it][0]), f2bf(vv[it][1]),
                              f2bf(vv[it][2]), f2bf(vv[it][3])};
      *(unsigned long long*)(win + wswz(bp9[it])) = *(const unsigned long long*)w4;
    }
  }

  // per-row constants
  int ohl[2], owr[2];
#pragma unroll
  for (int mf = 0; mf < 2; ++mf) {
    int m = wm0 + mf * 16 + (lane & 15);
    int p = p0 + m;
    if (p > 783) p = 783;
    int oh = p / 28;
    owr[mf] = p - oh * 28;
    ohl[mf] = (oh - ohmin) * 2;
  }
  const int lg = lane >> 4;
  const int ci0 = (lg & 1) * 8;
  const int lgh = lg >> 1;
  int brdo[2], brx[2];
#pragma unroll
  for (int nf = 0; nf < 2; ++nf) {
    int n = nf * 16 + (lane & 15);
    brdo[nf] = n * 128;
    brx[nf] = (n & 7) << 4;
  }

  f32x4 acc[2][2];
#pragma unroll
  for (int mf = 0; mf < 2; ++mf)
#pragma unroll
    for (int nf = 0; nf < 2; ++nf) acc[mf][nf] = (f32x4){0.f, 0.f, 0.f, 0.f};

  __syncthreads();

#pragma unroll
  for (int kt = 0; kt < 3; ++kt) {
#pragma unroll
    for (int ks = 0; ks < 2; ++ks) {
      const int g = kt * 4 + ks * 2 + lgh;
      const int kh = g / 3;
      const int kw = g - kh * 3;
      const bool gv = (g < 9);
      bf16x8 af[2];
#pragma unroll
      for (int mf = 0; mf < 2; ++mf) {
        int iwp = owr[mf] * 2 + kw;            // iw+1 >= 1 always
        int ihl = ohl[mf] + kh;
        int bp = gv ? ((ihl * 57 + iwp) * 32 + ci0 * 2)
                    : (13 * 57 * 32 + ci0 * 2); // zero row
        af[mf] = __builtin_bit_cast(bf16x8, *(const uint4*)(win + wswz(bp)));
      }
      bf16x8 bfv[2];
      const int cb = ks * 64 + ((lane >> 4) << 4);
#pragma unroll
      for (int nf = 0; nf < 2; ++nf)
        bfv[nf] = __builtin_bit_cast(bf16x8,
            *(const uint4*)(ldsB + kt * 4096 + brdo[nf] + (cb ^ brx[nf])));
#pragma unroll
      for (int mf = 0; mf < 2; ++mf)
#pragma unroll
        for (int nf = 0; nf < 2; ++nf)
          acc[mf][nf] = __builtin_amdgcn_mfma_f32_16x16x32_bf16(af[mf], bfv[nf], acc[mf][nf], 0, 0, 0);
    }
  }

  const int col = lane & 15;
  const int rg = (lane >> 4) * 4;
  const float b0 = bias[e * 32 + col];
  const float b1 = bias[e * 32 + 16 + col];
#pragma unroll
  for (int mf = 0; mf < 2; ++mf)
#pragma unroll
    for (int r = 0; r < 4; ++r) {
      int m = wm0 + mf * 16 + rg + r;
      int p = p0 + m;
      if (p < 784) {
        size_t ob = ((size_t)s * 784 + p) * 32;
        out[ob + col]      = f2bf(fmaxf(acc[mf][0][r] + b0, 0.f));
        out[ob + 16 + col] = f2bf(fmaxf(acc[mf][1][r] + b1, 0.f));
      }
    }
}

// ---------------- conv as implicit-GEMM MFMA (bf16 NHWC) — conv2/conv3 ----------------
template<int CIN, int H, int OH, int KREAL, int KP, int COUT,
         int WGM, int WGN, int MF, int NF>
__global__ __launch_bounds__(256) void conv_mfma(
    const unsigned short* __restrict__ in, const unsigned short* __restrict__ wb,
    const float* __restrict__ bias, const int* __restrict__ cnt,
    const int* __restrict__ perm, unsigned short* __restrict__ out) {
  constexpr int PerS = OH * OH;
  constexpr int BM = WGM * MF * 16;
  constexpr int BN = WGN * NF * 16;
  constexpr int AJ = BM / 32;
  constexpr int KT = KP / 64;
  constexpr int W = H;
  constexpr int BCH = BN / 32;

  int bm = blockIdx.x;
  int e = 0, row0 = 0, rows = 0;
  bool found = false;
  {
    int acc = 0, ebase = 0;
#pragma unroll
    for (int ee = 0; ee < 4; ++ee) {
      int er = cnt[ee] * PerS;
      int te = (er + BM - 1) / BM;
      if (!found && bm < acc + te) {
        e = ee;
        row0 = ebase + (bm - acc) * BM;
        rows = er - (bm - acc) * BM;
        if (rows > BM) rows = BM;
        found = true;
      }
      acc += te;
      ebase += er;
    }
  }
  if (!found) return;

  __shared__ __align__(16) char lds[BM * 128 + BN * 128];
  char* ldsB = lds + BM * 128;
  const int tid = threadIdx.x;
  const int lane = tid & 63;
  const int wid = tid >> 6;
  const int wm0 = (wid / WGN) * (MF * 16);
  const int wn0 = (wid % WGN) * (NF * 16);
  const int c16 = tid & 7;

  int ihc[AJ], iwc[AJ], abase[AJ], adso[AJ];
#pragma unroll
  for (int j = 0; j < AJ; ++j) {
    int r = (tid >> 3) + 32 * j;
    int gr = row0 + r;
    const int MAXR = 512 * PerS - 1;
    if (gr > MAXR) gr = MAXR;
    int sord = gr / PerS;
    int p = gr - sord * PerS;
    int s = perm[sord];
    int oh = p / OH, ow = p - oh * OH;
    ihc[j] = oh * 2 - 1;
    iwc[j] = ow * 2 - 1;
    abase[j] = s * (H * W);
    adso[j] = r * 128 + ((c16 * 16) ^ ((r & 7) << 4));
  }
  const unsigned short* wbe = wb + (size_t)e * COUT * KP;
  int bgo[BCH], bdso[BCH];
#pragma unroll
  for (int c = 0; c < BCH; ++c) {
    int cc = tid + 256 * c;
    int n = cc >> 3, cb = cc & 7;
    bgo[c] = n * KP + cb * 8;
    bdso[c] = n * 128 + ((cb * 16) ^ ((n & 7) << 4));
  }
  int ardo[MF], arx[MF], brdo[NF], brx[NF];
#pragma unroll
  for (int mf = 0; mf < MF; ++mf) {
    int r = wm0 + mf * 16 + (lane & 15);
    ardo[mf] = r * 128;
    arx[mf] = (r & 7) << 4;
  }
#pragma unroll
  for (int nf = 0; nf < NF; ++nf) {
    int n = wn0 + nf * 16 + (lane & 15);
    brdo[nf] = n * 128;
    brx[nf] = (n & 7) << 4;
  }

  auto loadA = [&](int kt, int j) -> uint4 {
    uint4 z; z.x = z.y = z.z = z.w = 0u;
    int kbase = kt * 64 + c16 * 8;
    if (kbase >= KREAL) return z;
    int g = kbase / CIN;
    int ci0 = kbase - g * CIN;
    int kh = g / 3, kw = g - (g / 3) * 3;
    int ih = ihc[j] + kh, iw = iwc[j] + kw;
    if ((unsigned)ih >= (unsigned)H || (unsigned)iw >= (unsigned)W) return z;
    const unsigned short* p = in + ((size_t)(abase[j] + ih * W + iw) * CIN + ci0);
    return *(const uint4*)p;
  };

  uint4 rA[AJ], rB[BCH];
#pragma unroll
  for (int j = 0; j < AJ; ++j) rA[j] = loadA(0, j);
#pragma unroll
  for (int c = 0; c < BCH; ++c) rB[c] = *(const uint4*)(wbe + bgo[c]);

  f32x4 acc[MF][NF];
#pragma unroll
  for (int mf = 0; mf < MF; ++mf)
#pragma unroll
    for (int nf = 0; nf < NF; ++nf) acc[mf][nf] = (f32x4){0.f, 0.f, 0.f, 0.f};

  for (int kt = 0; kt < KT; ++kt) {
    __syncthreads();
#pragma unroll
    for (int j = 0; j < AJ; ++j) *(uint4*)(lds + adso[j]) = rA[j];
#pragma unroll
    for (int c = 0; c < BCH; ++c) *(uint4*)(ldsB + bdso[c]) = rB[c];
    __syncthreads();
    if (kt + 1 < KT) {
#pragma unroll
      for (int j = 0; j < AJ; ++j) rA[j] = loadA(kt + 1, j);
#pragma unroll
      for (int c = 0; c < BCH; ++c) rB[c] = *(const uint4*)(wbe + bgo[c] + (kt + 1) * 64);
    }
#pragma unroll
    for (int ks = 0; ks < 2; ++ks) {
      int cb = ks * 64 + ((lane >> 4) << 4);
      bf16x8 af[MF], bfv[NF];
#pragma unroll
      for (int mf = 0; mf < MF; ++mf)
        af[mf] = __builtin_bit_cast(bf16x8, *(const uint4*)(lds + ardo[mf] + (cb ^ arx[mf])));
#pragma unroll
      for (int nf = 0; nf < NF; ++nf)
        bfv[nf] = __builtin_bit_cast(bf16x8, *(const uint4*)(ldsB + brdo[nf] + (cb ^ brx[nf])));
#pragma unroll
      for (int mf = 0; mf < MF; ++mf)
#pragma unroll
        for (int nf = 0; nf < NF; ++nf)
          acc[mf][nf] = __builtin_amdgcn_mfma_f32_16x16x32_bf16(af[mf], bfv[nf], acc[mf][nf], 0, 0, 0);
    }
  }

  const int col = lane & 15;
  const int rg = (lane >> 4) * 4;
#pragma unroll
  for (int mf = 0; mf < MF; ++mf) {
#pragma unroll
    for (int r = 0; r < 4; ++r) {
      int m = wm0 + mf * 16 + rg + r;
      if (m < rows) {
        int gr = row0 + m;
        int sord = gr / PerS;
        int p = gr - sord * PerS;
        int s = perm[sord];
        size_t ob = ((size_t)s * PerS + p) * COUT;
#pragma unroll
        for (int nf = 0; nf < NF; ++nf) {
          int co = wn0 + nf * 16 + col;
          float v = acc[mf][nf][r] + bias[e * COUT + co];
          out[ob + co] = f2bf(fmaxf(v, 0.f));
        }
      }
    }
  }
}

// ---------------- fused GEMM [512,6336]x[6336,256], 64x64 tiles, split-K=9 ----------------
__global__ __launch_bounds__(256) void fgemm_kernel(
    const unsigned short* __restrict__ x3, const unsigned short* __restrict__ tail,
    const unsigned short* __restrict__ fwT, float* __restrict__ partial) {
  constexpr int MF = 2, NF = 2;
  const int row0 = blockIdx.x * 64;
  const int nc0 = blockIdx.y * 64;
  const int kz = blockIdx.z * 704;
  __shared__ __align__(16) char lds[64 * 128 + 64 * 128];
  char* ldsB = lds + 64 * 128;
  const int tid = threadIdx.x;
  const int lane = tid & 63;
  const int wid = tid >> 6;
  const int wm0 = (wid >> 1) * 32;
  const int wn0 = (wid & 1) * 32;
  const int c16 = tid & 7;
  int arow[2], adso[2];
#pragma unroll
  for (int j = 0; j < 2; ++j) {
    int r = (tid >> 3) + 32 * j;
    arow[j] = row0 + r;
    adso[j] = r * 128 + ((c16 * 16) ^ ((r & 7) << 4));
  }
  int bgo[2], bdso[2];
#pragma unroll
  for (int c = 0; c < 2; ++c) {
    int cc = tid + 256 * c;
    int n = cc >> 3, cb = cc & 7;
    bgo[c] = (nc0 + n) * 6336 + kz + cb * 8;
    bdso[c] = n * 128 + ((cb * 16) ^ ((n & 7) << 4));
  }
  int ardo[MF], arx[MF], brdo[NF], brx[NF];
#pragma unroll
  for (int mf = 0; mf < MF; ++mf) {
    int r = wm0 + mf * 16 + (lane & 15);
    ardo[mf] = r * 128; arx[mf] = (r & 7) << 4;
  }
#pragma unroll
  for (int nf = 0; nf < NF; ++nf) {
    int n = wn0 + nf * 16 + (lane & 15);
    brdo[nf] = n * 128; brx[nf] = (n & 7) << 4;
  }
  auto loadA = [&](int kt, int j) -> uint4 {
    int k = kz + kt * 64 + c16 * 8;
    const unsigned short* p;
    if (k < 6272) p = x3 + (size_t)arow[j] * 6272 + k;
    else p = tail + arow[j] * 64 + (k - 6272);
    return *(const uint4*)p;
  };
  uint4 rA[2], rB[2];
#pragma unroll
  for (int j = 0; j < 2; ++j) rA[j] = loadA(0, j);
#pragma unroll
  for (int c = 0; c < 2; ++c) rB[c] = *(const uint4*)(fwT + bgo[c]);
  f32x4 acc[MF][NF];
#pragma unroll
  for (int mf = 0; mf < MF; ++mf)
#pragma unroll
    for (int nf = 0; nf < NF; ++nf) acc[mf][nf] = (f32x4){0.f, 0.f, 0.f, 0.f};

  for (int kt = 0; kt < 11; ++kt) {
    __syncthreads();
#pragma unroll
    for (int j = 0; j < 2; ++j) *(uint4*)(lds + adso[j]) = rA[j];
#pragma unroll
    for (int c = 0; c < 2; ++c) *(uint4*)(ldsB + bdso[c]) = rB[c];
    __syncthreads();
    if (kt + 1 < 11) {
#pragma unroll
      for (int j = 0; j < 2; ++j) rA[j] = loadA(kt + 1, j);
#pragma unroll
      for (int c = 0; c < 2; ++c) rB[c] = *(const uint4*)(fwT + bgo[c] + (kt + 1) * 64);
    }
#pragma unroll
    for (int ks = 0; ks < 2; ++ks) {
      int cb = ks * 64 + ((lane >> 4) << 4);
      bf16x8 af[MF], bfv[NF];
#pragma unroll
      for (int mf = 0; mf < MF; ++mf)
        af[mf] = __builtin_bit_cast(bf16x8, *(const uint4*)(lds + ardo[mf] + (cb ^ arx[mf])));
#pragma unroll
      for (int nf = 0; nf < NF; ++nf)
        bfv[nf] = __builtin_bit_cast(bf16x8, *(const uint4*)(ldsB + brdo[nf] + (cb ^ brx[nf])));
#pragma unroll
      for (int mf = 0; mf < MF; ++mf)
#pragma unroll
        for (int nf = 0; nf < NF; ++nf)
          acc[mf][nf] = __builtin_amdgcn_mfma_f32_16x16x32_bf16(af[mf], bfv[nf], acc[mf][nf], 0, 0, 0);
    }
  }
  const int col = lane & 15;
  const int rg = (lane >> 4) * 4;
  float* pz = partial + (size_t)blockIdx.z * 131072;
#pragma unroll
  for (int mf = 0; mf < MF; ++mf)
#pragma unroll
    for (int r = 0; r < 4; ++r) {
      int m = wm0 + mf * 16 + rg + r;
      int grow = row0 + m;
#pragma unroll
      for (int nf = 0; nf < 2; ++nf) {
        int n = nc0 + wn0 + nf * 16 + col;
        pz[grow * 256 + n] = acc[mf][nf][r];
      }
    }
}

// ---------------- reduce + head merged ----------------
__global__ __launch_bounds__(256) void reduce_head(const float* __restrict__ part,
                                                   const float* __restrict__ f_b,
                                                   const float* __restrict__ lmask,
                                                   const float* __restrict__ h_w,
                                                   const float* __restrict__ h_b,
                                                   float* __restrict__ logits) {
  int b = blockIdx.x, t = threadIdx.x;
  float s = f_b[t];
#pragma unroll
  for (int z = 0; z < 9; ++z) s += part[z * 131072 + b * 256 + t];
  __shared__ float o[256];
  o[t] = (lmask[b * 256 + t] != 0.f) ? fmaxf(s, 0.f) : 0.f;
  __syncthreads();
  if (t < 5) {
    float v = h_b[t];
    for (int n = 0; n < 256; ++n) v += o[n] * h_w[n * 5 + t];
    logits[b * 5 + t] = v;
  }
}

extern "C" void kernel_launch(void* const* d_in, const int* in_sizes, int n_in,
                              void* d_out, int out_size, void* d_ws, size_t ws_size,
                              hipStream_t stream) {
  (void)in_sizes; (void)n_in; (void)out_size; (void)ws_size;
  const float* img       = (const float*)d_in[0];
  const int*   text      = (const int*)d_in[1];
  const int*   pa        = (const int*)d_in[2];
  const float* emb_table = (const float*)d_in[3];
  const float* r_w1 = (const float*)d_in[4];
  const float* r_b1 = (const float*)d_in[5];
  const float* r_w2 = (const float*)d_in[6];
  const float* r_b2 = (const float*)d_in[7];
  const float* l_w1 = (const float*)d_in[8];
  const float* l_b1 = (const float*)d_in[9];
  const float* l_w2 = (const float*)d_in[10];
  const float* l_b2 = (const float*)d_in[11];
  const float* c1_w = (const float*)d_in[12];
  const float* c1_b = (const float*)d_in[13];
  const float* c2_w = (const float*)d_in[14];
  const float* c2_b = (const float*)d_in[15];
  const float* c3_w = (const float*)d_in[16];
  const float* c3_b = (const float*)d_in[17];
  const float* act_emb = (const float*)d_in[18];
  const float* f_w = (const float*)d_in[19];
  const float* f_b = (const float*)d_in[20];
  const float* h_w = (const float*)d_in[21];
  const float* h_b = (const float*)d_in[22];

  float* outf   = (float*)d_out;
  float* logits = outf;             // [512,5]
  float* rlog   = outf + 2560;      // [512,3,4]

  char* cur = (char*)d_ws;
  auto alloc = [&](size_t bytes) { char* r = cur; cur += (bytes + 255) & ~(size_t)255; return r; };
  float* lmask   = (float*)alloc(131072 * 4);
  int* eidx      = (int*)alloc(1536 * 4);
  int* cnt       = (int*)alloc(12 * 4);
  int* perm      = (int*)alloc(1536 * 4);
  unsigned short* wb1  = (unsigned short*)alloc((size_t)24576 * 2);
  unsigned short* wb2  = (unsigned short*)alloc((size_t)81920 * 2);
  unsigned short* wb3  = (unsigned short*)alloc((size_t)294912 * 2);
  unsigned short* fwT  = (unsigned short*)alloc((size_t)1622016 * 2);
  unsigned short* tailb= (unsigned short*)alloc((size_t)32768 * 2);
  unsigned short* x1b  = (unsigned short*)alloc((size_t)12845056 * 2);
  unsigned short* x2b  = (unsigned short*)alloc((size_t)6422528 * 2);
  unsigned short* x3b  = (unsigned short*)alloc((size_t)3211264 * 2);
  float* partial       = (float*)alloc((size_t)9 * 131072 * 4);

  prep_kernel<<<2179, 256, 0, stream>>>(text, emb_table,
                                        r_w1, r_b1, r_w2, r_b2,
                                        l_w1, l_b1, l_w2, l_b2,
                                        act_emb, pa,
                                        c1_w, c2_w, c3_w, f_w,
                                        rlog, eidx, lmask, tailb,
                                        wb1, wb2, wb3, fwT);

  conv1_fused<<<3587, 256, 0, stream>>>(img, wb1, c1_b, eidx, x1b, cnt, perm);
  conv_mfma<32, 28, 14, 288, 320, 64, 2, 2, 4, 2>
      <<<787, 256, 0, stream>>>(x1b, wb2, c2_b, cnt + 4, perm + 512, x2b);
  conv_mfma<64, 14, 7, 576, 576, 128, 1, 4, 4, 2>
      <<<395, 256, 0, stream>>>(x2b, wb3, c3_b, cnt + 8, perm + 1024, x3b);

  fgemm_kernel<<<dim3(8, 4, 9), 256, 0, stream>>>(x3b, tailb, fwT, partial);
  reduce_head<<<512, 256, 0, stream>>>(partial, f_b, lmask, h_w, h_b, logits);
}